// Round 22
// baseline (264.443 us; speedup 1.0000x reference)
//
#include <hip/hip_runtime.h>

typedef unsigned short u16;
typedef __attribute__((ext_vector_type(4))) float f32x4;
typedef __attribute__((ext_vector_type(16))) float f32x16;
typedef __attribute__((ext_vector_type(8))) short s16x8;
typedef __attribute__((ext_vector_type(8))) unsigned short u16x8;
typedef __attribute__((ext_vector_type(4))) unsigned short u16x4;

__device__ __forceinline__ float bf2f(u16 u) {
    union { unsigned int i; float f; } x; x.i = ((unsigned int)u) << 16; return x.f;
}
__device__ __forceinline__ u16 f2bf(float f) {
    union { float f; unsigned int i; } x; x.f = f;
    unsigned int r = x.i + 0x7FFFu + ((x.i >> 16) & 1u);
    return (u16)(r >> 16);
}
__device__ __forceinline__ void gload16(const void* g, void* l) {
    __builtin_amdgcn_global_load_lds((const __attribute__((address_space(1))) void*)g,
                                     (__attribute__((address_space(3))) void*)l, 16, 0, 0);
}
__device__ __forceinline__ unsigned cvtpk(float lo, float hi) {
    unsigned r;
    asm("v_cvt_pk_bf16_f32 %0, %1, %2" : "=v"(r) : "v"(lo), "v"(hi));
    return r;
}

// ---------------- constants ----------------
#define BATCH 2
#define SEQ 2048
#define HID 2048
#define NH 32
#define NKV 8
#define HD 64
#define TOK (BATCH * SEQ)
#define NQKV 3072
#define QSCALE 0.18033688011112042f   // 0.125 * log2(e), folded into Q

// ---------------- pre-pass: 4 weight transposes + X conversion in one dispatch ----------------
__global__ void k_prep(const float* __restrict__ Wq, const float* __restrict__ Wk,
                       const float* __restrict__ Wv, const float* __restrict__ Wo,
                       const float* __restrict__ hs,
                       u16* __restrict__ WTqkv, u16* __restrict__ WoT, u16* __restrict__ Xb) {
    __shared__ float tile[32][33];
    const int z = blockIdx.z;
    int tx = threadIdx.x, ty = threadIdx.y;   // (32, 8)
    if (z == 4) {
        int blk = blockIdx.y * 64 + blockIdx.x;
        size_t base = ((size_t)blk * 256 + (ty * 32 + tx)) * 8;
        f32x4 v0 = *(const f32x4*)(hs + base);
        f32x4 v1 = *(const f32x4*)(hs + base + 4);
        u16x8 o;
        o[0] = f2bf(v0[0]); o[1] = f2bf(v0[1]); o[2] = f2bf(v0[2]); o[3] = f2bf(v0[3]);
        o[4] = f2bf(v1[0]); o[5] = f2bf(v1[1]); o[6] = f2bf(v1[2]); o[7] = f2bf(v1[3]);
        *(u16x8*)(Xb + base) = o;
        return;
    }
    const float* src;
    u16* dst;
    int N;
    if (z == 0)      { src = Wq; dst = WTqkv;                              N = HID; }
    else if (z == 1) { src = Wk; dst = WTqkv + (size_t)HID * HID;          N = 512; }
    else if (z == 2) { src = Wv; dst = WTqkv + (size_t)(HID + 512) * HID;  N = 512; }
    else             { src = Wo; dst = WoT;                                N = HID; }
    int n0 = blockIdx.x * 32, k0 = blockIdx.y * 32;
    if (n0 >= N) return;
#pragma unroll
    for (int i = 0; i < 4; i++)
        tile[ty + i * 8][tx] = src[(size_t)(k0 + ty + i * 8) * N + n0 + tx];
    __syncthreads();
#pragma unroll
    for (int i = 0; i < 4; i++) {
        int n = n0 + ty + i * 8;
        dst[(size_t)n * HID + k0 + tx] = f2bf(tile[tx][ty + i * 8]);
    }
}

// per-head transpose: src [SEQ][HD] bf16 -> dst [HD][SEQ] bf16
__global__ void k_transpose_v(const u16* __restrict__ src, u16* __restrict__ dst) {
    __shared__ u16 tile[32][34];
    const u16* s = src + (size_t)blockIdx.z * SEQ * HD;
    u16* d = dst + (size_t)blockIdx.z * SEQ * HD;
    int d0 = blockIdx.x * 32;
    int s0 = blockIdx.y * 32;
    int tx = threadIdx.x, ty = threadIdx.y;
#pragma unroll
    for (int i = 0; i < 4; i++)
        tile[ty + i * 8][tx] = s[(size_t)(s0 + ty + i * 8) * HD + d0 + tx];
    __syncthreads();
#pragma unroll
    for (int i = 0; i < 4; i++)
        d[(size_t)(d0 + ty + i * 8) * SEQ + s0 + tx] = tile[tx][ty + i * 8];
}

// ---------------- QKV GEMM: 128x256 8-wave pipelined (Wo-structure clone) + fused epilogue ----------------
// grid = 32x12 = 384 blocks (%8==0). Per-wave 64 rows x 64 cols = one head.
__global__ __launch_bounds__(512, 1) void k_gemm_qkv_wo(const u16* __restrict__ A, const u16* __restrict__ BT,
                                                        const float* __restrict__ bq, const float* __restrict__ bk,
                                                        const float* __restrict__ bv,
                                                        const float* __restrict__ qn_w, const float* __restrict__ kn_w,
                                                        const float* __restrict__ cosT, const float* __restrict__ sinT,
                                                        u16* __restrict__ Qp, u16* __restrict__ Kp, u16* __restrict__ Vp,
                                                        int K, int lda, int ldb) {
    __shared__ u16 LA[2][128 * 64];
    __shared__ u16 LB[2][256 * 64];
    const int tid = threadIdx.x;
    const int w = tid >> 6, lane = tid & 63;
    const int wm = w >> 2, wn = w & 3;            // wave grid 2M x 4N
    const int lr = lane & 15, g = lane >> 4;
    const int nwg = gridDim.x;                    // 384, %8==0
    int bid = blockIdx.x;
    const int cpx = nwg >> 3;
    bid = (bid & 7) * cpx + (bid >> 3);           // XCD-bijective
    const int gxn = NQKV / 256;                   // 12
    const int brow = (bid / gxn) * 128, bcol = (bid % gxn) * 256;

    const int lrow8 = lane >> 3;
    const int gs = (lane & 7) ^ lrow8;
    const u16* Ag[2]; const u16* Bg[4];
#pragma unroll
    for (int p = 0; p < 2; p++) {
        int row = (w * 2 + p) * 8 + lrow8;
        Ag[p] = A + (size_t)(brow + row) * lda + gs * 8;
    }
#pragma unroll
    for (int p = 0; p < 4; p++) {
        int row = (w * 4 + p) * 8 + lrow8;
        Bg[p] = BT + (size_t)(bcol + row) * ldb + gs * 8;
    }

    f32x4 acc[4][4] = {};

#pragma unroll
    for (int p = 0; p < 2; p++) gload16(Ag[p], &LA[0][(w * 2 + p) * 512]);
#pragma unroll
    for (int p = 0; p < 4; p++) gload16(Bg[p], &LB[0][(w * 4 + p) * 512]);
    asm volatile("s_waitcnt vmcnt(0)" ::: "memory");
    __builtin_amdgcn_s_barrier();
    asm volatile("" ::: "memory");

    const int NT = K >> 6;
    int cur = 0;
    for (int tk = 0; tk < NT; tk++) {
        const u16* Al = &LA[cur][0];
        const u16* Bl = &LB[cur][0];
        u16* An = &LA[cur ^ 1][0];
        u16* Bn = &LB[cur ^ 1][0];
        const int knext = (tk + 1) << 6;
        const bool pf = (tk + 1 < NT);
        s16x8 bfr[4][2];
#pragma unroll
        for (int p = 0; p < 4; p++) {      // phase p computes mi = p
            s16x8 af[2];
            const char* rowpA = (const char*)Al + (size_t)(wm * 64 + p * 16 + lr) * 128;
#pragma unroll
            for (int kk = 0; kk < 2; kk++)
                af[kk] = *(const s16x8*)(rowpA + (((kk * 4 + g) ^ (lr & 7)) << 4));
            if (p == 0) {
#pragma unroll
                for (int ni = 0; ni < 4; ni++) {
                    const char* rowp = (const char*)Bl + (size_t)(wn * 64 + ni * 16 + lr) * 128;
#pragma unroll
                    for (int kk = 0; kk < 2; kk++)
                        bfr[ni][kk] = *(const s16x8*)(rowp + (((kk * 4 + g) ^ (lr & 7)) << 4));
                }
            }
            if (pf) {
                if (p == 0) {
                    gload16(Ag[0] + knext, &An[(w * 2 + 0) * 512]);
                    gload16(Ag[1] + knext, &An[(w * 2 + 1) * 512]);
                } else if (p == 1) {
                    gload16(Bg[0] + knext, &Bn[(w * 4 + 0) * 512]);
                    gload16(Bg[1] + knext, &Bn[(w * 4 + 1) * 512]);
                } else if (p == 2) {
                    gload16(Bg[2] + knext, &Bn[(w * 4 + 2) * 512]);
                    gload16(Bg[3] + knext, &Bn[(w * 4 + 3) * 512]);
                }
            }
            __builtin_amdgcn_s_barrier();
            __builtin_amdgcn_s_setprio(1);
#pragma unroll
            for (int ni = 0; ni < 4; ni++) {
                acc[p][ni] = __builtin_amdgcn_mfma_f32_16x16x32_bf16(af[0], bfr[ni][0], acc[p][ni], 0, 0, 0);
                acc[p][ni] = __builtin_amdgcn_mfma_f32_16x16x32_bf16(af[1], bfr[ni][1], acc[p][ni], 0, 0, 0);
            }
            __builtin_amdgcn_s_setprio(0);
            __builtin_amdgcn_s_barrier();
        }
        if (pf) asm volatile("s_waitcnt vmcnt(0)" ::: "memory");
        __builtin_amdgcn_s_barrier();
        asm volatile("" ::: "memory");
        cur ^= 1;
    }

    // ---- fused epilogue: bias + RMSNorm + RoPE, write Q/K/V final layouts ----
    const int head = (bcol >> 6) + wn;            // wave-uniform, 0..47
    const float* bptr = (head < 32) ? (bq + head * 64)
                       : (head < 40) ? (bk + (head - 32) * 64)
                                     : (bv + (head - 40) * 64);
    const float bz0 = bptr[0 * 16 + lr], bz1 = bptr[1 * 16 + lr];
    const float bz2 = bptr[2 * 16 + lr], bz3 = bptr[3 * 16 + lr];
    const float nw0 = (head < 32) ? qn_w[0 * 16 + lr] : kn_w[0 * 16 + lr];
    const float nw1 = (head < 32) ? qn_w[1 * 16 + lr] : kn_w[1 * 16 + lr];
    const float nw2 = (head < 32) ? qn_w[2 * 16 + lr] : kn_w[2 * 16 + lr];
    const float nw3 = (head < 32) ? qn_w[3 * 16 + lr] : kn_w[3 * 16 + lr];
#pragma unroll
    for (int mi = 0; mi < 4; mi++) {
#pragma unroll
        for (int r = 0; r < 4; r++) {
            int row = brow + wm * 64 + mi * 16 + g * 4 + r;   // token
            int b = row >> 11, s = row & 2047;
            float v[4];
            v[0] = acc[mi][0][r] + bz0;
            v[1] = acc[mi][1][r] + bz1;
            v[2] = acc[mi][2][r] + bz2;
            v[3] = acc[mi][3][r] + bz3;
            if (head < 40) {
                float ss = v[0] * v[0] + v[1] * v[1] + v[2] * v[2] + v[3] * v[3];
                ss += __shfl_xor(ss, 1);
                ss += __shfl_xor(ss, 2);
                ss += __shfl_xor(ss, 4);
                ss += __shfl_xor(ss, 8);
                float rin = rsqrtf(ss * (1.0f / 64.0f) + 1e-6f);
                float xn[4];
                xn[0] = v[0] * rin * nw0;
                xn[1] = v[1] * rin * nw1;
                xn[2] = v[2] * rin * nw2;
                xn[3] = v[3] * rin * nw3;
                const float* cr = cosT + (size_t)s * HD;
                const float* sr = sinT + (size_t)s * HD;
                float o[4];
#pragma unroll
                for (int ni = 0; ni < 4; ni++) {
                    int d = ni * 16 + lr;
                    float part = xn[ni ^ 2];
                    float sign = (d < 32) ? -1.f : 1.f;
                    o[ni] = xn[ni] * cr[d] + sign * part * sr[d];
                }
                if (head < 32) {
                    u16* qrow = Qp + (((size_t)(b * NH + head) * SEQ + s) * HD);
#pragma unroll
                    for (int ni = 0; ni < 4; ni++) qrow[ni * 16 + lr] = f2bf(o[ni] * QSCALE);
                } else {
                    u16* krow = Kp + (((size_t)(b * NKV + head - 32) * SEQ + s) * HD);
#pragma unroll
                    for (int ni = 0; ni < 4; ni++) krow[ni * 16 + lr] = f2bf(o[ni]);
                }
            } else {
                u16* vrow = Vp + (((size_t)(b * NKV + head - 40) * SEQ + s) * HD);
#pragma unroll
                for (int ni = 0; ni < 4; ni++) vrow[ni * 16 + lr] = f2bf(v[ni]);
            }
        }
    }
}

// ---------------- GEMM: 128x256 8-wave pipelined (used for Wo, f32 out) ----------------
__global__ __launch_bounds__(512, 1) void k_gemm_wo(const u16* __restrict__ A, const u16* __restrict__ BT,
                                                    const float* __restrict__ bias, float* __restrict__ Cout,
                                                    int gxn, int K, int lda, int ldb, int N) {
    __shared__ u16 LA[2][128 * 64];
    __shared__ u16 LB[2][256 * 64];
    const int tid = threadIdx.x;
    const int w = tid >> 6, lane = tid & 63;
    const int wm = w >> 2, wn = w & 3;            // wave grid 2M x 4N
    const int lr = lane & 15, g = lane >> 4;
    const int nwg = gridDim.x;
    int bid = blockIdx.x;
    const int cpx = nwg >> 3;
    bid = (bid & 7) * cpx + (bid >> 3);           // XCD-bijective (nwg%8==0)
    const int brow = (bid / gxn) * 128, bcol = (bid % gxn) * 256;

    const int lrow8 = lane >> 3;
    const int gs = (lane & 7) ^ lrow8;
    const u16* Ag[2]; const u16* Bg[4];
#pragma unroll
    for (int p = 0; p < 2; p++) {
        int row = (w * 2 + p) * 8 + lrow8;
        Ag[p] = A + (size_t)(brow + row) * lda + gs * 8;
    }
#pragma unroll
    for (int p = 0; p < 4; p++) {
        int row = (w * 4 + p) * 8 + lrow8;
        Bg[p] = BT + (size_t)(bcol + row) * ldb + gs * 8;
    }

    f32x4 acc[4][4] = {};

#pragma unroll
    for (int p = 0; p < 2; p++) gload16(Ag[p], &LA[0][(w * 2 + p) * 512]);
#pragma unroll
    for (int p = 0; p < 4; p++) gload16(Bg[p], &LB[0][(w * 4 + p) * 512]);
    asm volatile("s_waitcnt vmcnt(0)" ::: "memory");
    __builtin_amdgcn_s_barrier();
    asm volatile("" ::: "memory");

    const int NT = K >> 6;
    int cur = 0;
    for (int tk = 0; tk < NT; tk++) {
        const u16* Al = &LA[cur][0];
        const u16* Bl = &LB[cur][0];
        u16* An = &LA[cur ^ 1][0];
        u16* Bn = &LB[cur ^ 1][0];
        const int knext = (tk + 1) << 6;
        const bool pf = (tk + 1 < NT);
        s16x8 bfr[4][2];
#pragma unroll
        for (int p = 0; p < 4; p++) {      // phase p computes mi = p
            s16x8 af[2];
            const char* rowpA = (const char*)Al + (size_t)(wm * 64 + p * 16 + lr) * 128;
#pragma unroll
            for (int kk = 0; kk < 2; kk++)
                af[kk] = *(const s16x8*)(rowpA + (((kk * 4 + g) ^ (lr & 7)) << 4));
            if (p == 0) {
#pragma unroll
                for (int ni = 0; ni < 4; ni++) {
                    const char* rowp = (const char*)Bl + (size_t)(wn * 64 + ni * 16 + lr) * 128;
#pragma unroll
                    for (int kk = 0; kk < 2; kk++)
                        bfr[ni][kk] = *(const s16x8*)(rowp + (((kk * 4 + g) ^ (lr & 7)) << 4));
                }
            }
            if (pf) {
                if (p == 0) {
                    gload16(Ag[0] + knext, &An[(w * 2 + 0) * 512]);
                    gload16(Ag[1] + knext, &An[(w * 2 + 1) * 512]);
                } else if (p == 1) {
                    gload16(Bg[0] + knext, &Bn[(w * 4 + 0) * 512]);
                    gload16(Bg[1] + knext, &Bn[(w * 4 + 1) * 512]);
                } else if (p == 2) {
                    gload16(Bg[2] + knext, &Bn[(w * 4 + 2) * 512]);
                    gload16(Bg[3] + knext, &Bn[(w * 4 + 3) * 512]);
                }
            }
            __builtin_amdgcn_s_barrier();
            __builtin_amdgcn_s_setprio(1);
#pragma unroll
            for (int ni = 0; ni < 4; ni++) {
                acc[p][ni] = __builtin_amdgcn_mfma_f32_16x16x32_bf16(af[0], bfr[ni][0], acc[p][ni], 0, 0, 0);
                acc[p][ni] = __builtin_amdgcn_mfma_f32_16x16x32_bf16(af[1], bfr[ni][1], acc[p][ni], 0, 0, 0);
            }
            __builtin_amdgcn_s_setprio(0);
            __builtin_amdgcn_s_barrier();
        }
        if (pf) asm volatile("s_waitcnt vmcnt(0)" ::: "memory");
        __builtin_amdgcn_s_barrier();
        asm volatile("" ::: "memory");
        cur ^= 1;
    }

#pragma unroll
    for (int mi = 0; mi < 4; mi++) {
#pragma unroll
        for (int ni = 0; ni < 4; ni++) {
#pragma unroll
            for (int r = 0; r < 4; r++) {
                int row = brow + wm * 64 + mi * 16 + g * 4 + r;
                int col = bcol + wn * 64 + ni * 16 + lr;
                Cout[(size_t)row * N + col] = acc[mi][ni][r] + bias[col];
            }
        }
    }
}

// ---------------- MFMA flash attention v4.1 (r17 verbatim, measured ~90us) ----------------
__global__ __launch_bounds__(256) void k_attn_mfma(const u16* __restrict__ Qp, const u16* __restrict__ Kp,
                                                   const u16* __restrict__ VpT, u16* __restrict__ AO) {
    __shared__ u16 K_lds[64 * 64];    // [key][d], 16B slots XOR'd by key&7
    __shared__ u16 VT_lds[64 * 64];   // [d][key], 16B slots XOR'd by d&7
    __shared__ u16 P_lds[4][32][76];  // per-wave, [q][key], pad 76
    const int bid = blockIdx.x;
    const int qt = 15 - (bid >> 6);   // heavy tiles first
    const int hh = bid & 63;
    const int b = hh >> 5, h = hh & 31, kvh = h >> 2;
    const int t = threadIdx.x, w = t >> 6, lane = t & 63;
    const int q5 = lane & 31, hi = lane >> 5;
    const int qwb = qt * 128 + w * 32;
    const int q_abs = qwb + q5;

    const u16* Qb = Qp + (size_t)(b * NH + h) * SEQ * HD;
    const u16* Kb = Kp + (size_t)(b * NKV + kvh) * SEQ * HD;
    const u16* Vb = VpT + (size_t)(b * NKV + kvh) * HD * SEQ;

    s16x8 qf0 = *(const s16x8*)(Qb + (size_t)q_abs * HD + 0 * 16 + hi * 8);
    s16x8 qf1 = *(const s16x8*)(Qb + (size_t)q_abs * HD + 1 * 16 + hi * 8);
    s16x8 qf2 = *(const s16x8*)(Qb + (size_t)q_abs * HD + 2 * 16 + hi * 8);
    s16x8 qf3 = *(const s16x8*)(Qb + (size_t)q_abs * HD + 3 * 16 + hi * 8);

    f32x16 O0, O1;
#pragma unroll
    for (int r = 0; r < 16; r++) { O0[r] = 0.f; O1[r] = 0.f; }
    float m = -1e30f, l = 0.f;

    const int swz = (q5 & 7) << 4;
    const int nkt = 2 * (qt + 1);
    for (int kt = 0; kt < nkt; kt++) {
        const int k0 = kt * 64;
        __syncthreads();
#pragma unroll
        for (int i = 0; i < 2; i++) {
            int c = (w * 2 + i) * 64 + lane;
            int row = c >> 3, gslot = (c & 7) ^ (row & 7);
            gload16(Kb + (size_t)(k0 + row) * HD + gslot * 8, (char*)K_lds + (size_t)(w * 2 + i) * 1024);
            gload16(Vb + (size_t)row * SEQ + k0 + gslot * 8, (char*)VT_lds + (size_t)(w * 2 + i) * 1024);
        }
        __syncthreads();
        if (k0 > qwb + 31) continue;

        f32x16 s0, s1;
#pragma unroll
        for (int r = 0; r < 16; r++) { s0[r] = 0.f; s1[r] = 0.f; }
        __builtin_amdgcn_s_setprio(1);
#pragma unroll
        for (int dblk = 0; dblk < 4; dblk++) {
            s16x8 kf0 = *(const s16x8*)((const char*)K_lds + q5 * 128 + ((dblk * 32 + hi * 16) ^ swz));
            s16x8 kf1 = *(const s16x8*)((const char*)K_lds + (32 + q5) * 128 + ((dblk * 32 + hi * 16) ^ swz));
            s16x8 qq = (dblk == 0) ? qf0 : (dblk == 1) ? qf1 : (dblk == 2) ? qf2 : qf3;
            s0 = __builtin_amdgcn_mfma_f32_32x32x16_bf16(kf0, qq, s0, 0, 0, 0);
            s1 = __builtin_amdgcn_mfma_f32_32x32x16_bf16(kf1, qq, s1, 0, 0, 0);
        }
        __builtin_amdgcn_s_setprio(0);

        if (k0 + 63 > qwb) {
            const int qrel = q_abs - k0;
#pragma unroll
            for (int r = 0; r < 16; r++) {
                int kr = (r & 3) + 8 * (r >> 2) + 4 * hi;
                if (kr > qrel) s0[r] = -1e30f;
                if (kr + 32 > qrel) s1[r] = -1e30f;
            }
        }

        float mt = -1e30f;
#pragma unroll
        for (int r = 0; r < 16; r++) { mt = fmaxf(mt, s0[r]); mt = fmaxf(mt, s1[r]); }
        mt = fmaxf(mt, __shfl_xor(mt, 32));
        if (!__all(mt <= m + 8.0f)) {
            float mn = fmaxf(m, mt);
            float f = exp2f(m - mn);
            l *= f;
#pragma unroll
            for (int r = 0; r < 16; r++) { O0[r] *= f; O1[r] *= f; }
            m = mn;
        }
        float ps = 0.f;
#pragma unroll
        for (int r = 0; r < 16; r++) {
            float p0 = exp2f(s0[r] - m);
            float p1 = exp2f(s1[r] - m);
            s0[r] = p0; s1[r] = p1;
            ps += p0 + p1;
        }
        ps += __shfl_xor(ps, 32);
        l += ps;

#pragma unroll
        for (int i = 0; i < 8; i++) {
            int key = 2 * (i & 1) + 8 * (i >> 1) + 4 * hi;
            *(unsigned*)&P_lds[w][q5][key]      = cvtpk(s0[2 * i], s0[2 * i + 1]);
            *(unsigned*)&P_lds[w][q5][key + 32] = cvtpk(s1[2 * i], s1[2 * i + 1]);
        }

        __builtin_amdgcn_s_setprio(1);
#pragma unroll
        for (int ks = 0; ks < 4; ks++) {
            s16x8 pb  = *(const s16x8*)&P_lds[w][q5][ks * 16 + hi * 8];
            s16x8 vf0 = *(const s16x8*)((const char*)VT_lds + q5 * 128 + ((ks * 32 + hi * 16) ^ swz));
            s16x8 vf1 = *(const s16x8*)((const char*)VT_lds + (32 + q5) * 128 + ((ks * 32 + hi * 16) ^ swz));
            O0 = __builtin_amdgcn_mfma_f32_32x32x16_bf16(vf0, pb, O0, 0, 0, 0);
            O1 = __builtin_amdgcn_mfma_f32_32x32x16_bf16(vf1, pb, O1, 0, 0, 0);
        }
        __builtin_amdgcn_s_setprio(0);
    }

    float inv = 1.0f / l;
    u16* orow = AO + (size_t)(b * SEQ + q_abs) * (NH * HD) + h * HD;
#pragma unroll
    for (int db = 0; db < 2; db++) {
#pragma unroll
        for (int g2 = 0; g2 < 4; g2++) {
            u16x4 wv;
#pragma unroll
            for (int i2 = 0; i2 < 4; i2++) {
                float v = (db == 0 ? O0[g2 * 4 + i2] : O1[g2 * 4 + i2]) * inv;
                wv[i2] = f2bf(v);
            }
            *(u16x4*)(orow + db * 32 + g2 * 8 + hi * 4) = wv;
        }
    }
}

// ---------------- launch ----------------
extern "C" void kernel_launch(void* const* d_in, const int* in_sizes, int n_in,
                              void* d_out, int out_size, void* d_ws, size_t ws_size,
                              hipStream_t stream) {
    const float* hs   = (const float*)d_in[0];
    const float* Wq   = (const float*)d_in[1];
    const float* bq   = (const float*)d_in[2];
    const float* Wk   = (const float*)d_in[3];
    const float* bk   = (const float*)d_in[4];
    const float* Wv   = (const float*)d_in[5];
    const float* bv   = (const float*)d_in[6];
    const float* Wo   = (const float*)d_in[7];
    const float* bo   = (const float*)d_in[8];
    const float* qn_w = (const float*)d_in[9];
    const float* kn_w = (const float*)d_in[10];
    const float* cosT = (const float*)d_in[11];
    const float* sinT = (const float*)d_in[12];

    char* ws = (char*)d_ws;
    size_t off = 0;
    auto alloc = [&](size_t bytes) { char* p = ws + off; off = (off + bytes + 255) & ~(size_t)255; return p; };
    u16*   Xb    = (u16*)  alloc((size_t)TOK * HID * 2);
    u16*   WTqkv = (u16*)  alloc((size_t)NQKV * HID * 2);
    u16*   WoT   = (u16*)  alloc((size_t)HID * HID * 2);
    u16*   Qp    = (u16*)  alloc((size_t)BATCH * NH * SEQ * HD * 2);
    u16*   Kp    = (u16*)  alloc((size_t)BATCH * NKV * SEQ * HD * 2);
    u16*   Vp    = (u16*)  alloc((size_t)BATCH * NKV * SEQ * HD * 2);
    u16*   VpT   = (u16*)  alloc((size_t)BATCH * NKV * SEQ * HD * 2);
    u16*   AO    = (u16*)  alloc((size_t)TOK * HID * 2);
    (void)ws_size;

    dim3 tb(32, 8);
    // weight transposes + X conversion in one dispatch
    k_prep<<<dim3(64, 64, 5), tb, 0, stream>>>(Wq, Wk, Wv, Wo, hs, WTqkv, WoT, Xb);
    // QKV GEMM (128x256 Wo-structure clone, grid 384) + fused bias/RMSNorm/RoPE
    k_gemm_qkv_wo<<<dim3((TOK / 128) * (NQKV / 256)), 512, 0, stream>>>(
        Xb, WTqkv, bq, bk, bv, qn_w, kn_w, cosT, sinT, Qp, Kp, Vp, HID, HID, HID);
    // V transpose per head
    k_transpose_v<<<dim3(HD / 32, SEQ / 32, BATCH * NKV), tb, 0, stream>>>(Vp, VpT);
    // MFMA flash attention (r17 verbatim)
    k_attn_mfma<<<BATCH * NH * (SEQ / 128), 256, 0, stream>>>(Qp, Kp, VpT, AO);
    // output projection (128x256 pipelined) -> f32 d_out: grid 32*8 = 256 blocks (%8==0)
    k_gemm_wo<<<dim3((TOK / 128) * (HID / 256)), 512, 0, stream>>>(AO, WoT, bo, (float*)d_out,
                                                                    HID / 256, HID, HID, HID, HID);
}

// Round 23
// 226.861 us; speedup vs baseline: 1.1657x; 1.1657x over previous
//
#include <hip/hip_runtime.h>

typedef unsigned short u16;
typedef __attribute__((ext_vector_type(4))) float f32x4;
typedef __attribute__((ext_vector_type(16))) float f32x16;
typedef __attribute__((ext_vector_type(8))) short s16x8;
typedef __attribute__((ext_vector_type(8))) unsigned short u16x8;
typedef __attribute__((ext_vector_type(4))) unsigned short u16x4;

__device__ __forceinline__ float bf2f(u16 u) {
    union { unsigned int i; float f; } x; x.i = ((unsigned int)u) << 16; return x.f;
}
__device__ __forceinline__ u16 f2bf(float f) {
    union { float f; unsigned int i; } x; x.f = f;
    unsigned int r = x.i + 0x7FFFu + ((x.i >> 16) & 1u);
    return (u16)(r >> 16);
}
__device__ __forceinline__ void gload16(const void* g, void* l) {
    __builtin_amdgcn_global_load_lds((const __attribute__((address_space(1))) void*)g,
                                     (__attribute__((address_space(3))) void*)l, 16, 0, 0);
}
__device__ __forceinline__ unsigned cvtpk(float lo, float hi) {
    unsigned r;
    asm("v_cvt_pk_bf16_f32 %0, %1, %2" : "=v"(r) : "v"(lo), "v"(hi));
    return r;
}

// ---------------- constants ----------------
#define BATCH 2
#define SEQ 2048
#define HID 2048
#define NH 32
#define NKV 8
#define HD 64
#define TOK (BATCH * SEQ)
#define NQKV 3072
#define QSCALE 0.18033688011112042f   // 0.125 * log2(e), folded into Q

// ---------------- pre-pass: 4 weight transposes + X conversion in one dispatch ----------------
__global__ void k_prep(const float* __restrict__ Wq, const float* __restrict__ Wk,
                       const float* __restrict__ Wv, const float* __restrict__ Wo,
                       const float* __restrict__ hs,
                       u16* __restrict__ WTqkv, u16* __restrict__ WoT, u16* __restrict__ Xb) {
    __shared__ float tile[32][33];
    const int z = blockIdx.z;
    int tx = threadIdx.x, ty = threadIdx.y;   // (32, 8)
    if (z == 4) {
        int blk = blockIdx.y * 64 + blockIdx.x;
        size_t base = ((size_t)blk * 256 + (ty * 32 + tx)) * 8;
        f32x4 v0 = *(const f32x4*)(hs + base);
        f32x4 v1 = *(const f32x4*)(hs + base + 4);
        u16x8 o;
        o[0] = f2bf(v0[0]); o[1] = f2bf(v0[1]); o[2] = f2bf(v0[2]); o[3] = f2bf(v0[3]);
        o[4] = f2bf(v1[0]); o[5] = f2bf(v1[1]); o[6] = f2bf(v1[2]); o[7] = f2bf(v1[3]);
        *(u16x8*)(Xb + base) = o;
        return;
    }
    const float* src;
    u16* dst;
    int N;
    if (z == 0)      { src = Wq; dst = WTqkv;                              N = HID; }
    else if (z == 1) { src = Wk; dst = WTqkv + (size_t)HID * HID;          N = 512; }
    else if (z == 2) { src = Wv; dst = WTqkv + (size_t)(HID + 512) * HID;  N = 512; }
    else             { src = Wo; dst = WoT;                                N = HID; }
    int n0 = blockIdx.x * 32, k0 = blockIdx.y * 32;
    if (n0 >= N) return;
#pragma unroll
    for (int i = 0; i < 4; i++)
        tile[ty + i * 8][tx] = src[(size_t)(k0 + ty + i * 8) * N + n0 + tx];
    __syncthreads();
#pragma unroll
    for (int i = 0; i < 4; i++) {
        int n = n0 + ty + i * 8;
        dst[(size_t)n * HID + k0 + tx] = f2bf(tile[tx][ty + i * 8]);
    }
}

// per-head transpose: src [SEQ][HD] bf16 -> dst [HD][SEQ] bf16
__global__ void k_transpose_v(const u16* __restrict__ src, u16* __restrict__ dst) {
    __shared__ u16 tile[32][34];
    const u16* s = src + (size_t)blockIdx.z * SEQ * HD;
    u16* d = dst + (size_t)blockIdx.z * SEQ * HD;
    int d0 = blockIdx.x * 32;
    int s0 = blockIdx.y * 32;
    int tx = threadIdx.x, ty = threadIdx.y;
#pragma unroll
    for (int i = 0; i < 4; i++)
        tile[ty + i * 8][tx] = s[(size_t)(s0 + ty + i * 8) * HD + d0 + tx];
    __syncthreads();
#pragma unroll
    for (int i = 0; i < 4; i++)
        d[(size_t)(d0 + ty + i * 8) * SEQ + s0 + tx] = tile[tx][ty + i * 8];
}

// ---------------- GEMM: 256x256 8-wave pipelined + fused bias/RMSNorm/RoPE epilogue ----------------
__global__ __launch_bounds__(512, 1) void k_gemm256_qkv(const u16* __restrict__ A, const u16* __restrict__ BT,
                                                        const float* __restrict__ bq, const float* __restrict__ bk,
                                                        const float* __restrict__ bv,
                                                        const float* __restrict__ qn_w, const float* __restrict__ kn_w,
                                                        const float* __restrict__ cosT, const float* __restrict__ sinT,
                                                        u16* __restrict__ Qp, u16* __restrict__ Kp, u16* __restrict__ Vp,
                                                        int gxn, int K, int lda, int ldb) {
    __shared__ u16 LDS[2][2][256 * 64];   // [buf][A/B][row*64+col] swizzled
    const int tid = threadIdx.x;
    const int w = tid >> 6, lane = tid & 63;
    const int wm = w >> 2, wn = w & 3;            // wave grid 2M x 4N
    const int lr = lane & 15, g = lane >> 4;
    const int nwg = gridDim.x;
    int bid = blockIdx.x;
    const int cpx = nwg >> 3;
    bid = (bid & 7) * cpx + (bid >> 3);           // XCD-bijective (nwg%8==0)
    const int brow = (bid / gxn) * 256, bcol = (bid % gxn) * 256;

    const int lrow8 = lane >> 3;
    const int gs = (lane & 7) ^ lrow8;
    const u16* Ag[4]; const u16* Bg[4];
#pragma unroll
    for (int p = 0; p < 4; p++) {
        int row = (w * 4 + p) * 8 + lrow8;
        Ag[p] = A + (size_t)(brow + row) * lda + gs * 8;
        Bg[p] = BT + (size_t)(bcol + row) * ldb + gs * 8;
    }

    f32x4 acc[8][4] = {};

#pragma unroll
    for (int p = 0; p < 4; p++) {
        gload16(Ag[p], &LDS[0][0][(w * 4 + p) * 512]);
        gload16(Bg[p], &LDS[0][1][(w * 4 + p) * 512]);
    }
    asm volatile("s_waitcnt vmcnt(0)" ::: "memory");
    __builtin_amdgcn_s_barrier();
    asm volatile("" ::: "memory");

    const int NT = K >> 6;
    int cur = 0;
    for (int tk = 0; tk < NT; tk++) {
        const u16* Al = &LDS[cur][0][0];
        const u16* Bl = &LDS[cur][1][0];
        u16* An = &LDS[cur ^ 1][0][0];
        u16* Bn = &LDS[cur ^ 1][1][0];
        const int knext = (tk + 1) << 6;
        const bool pf = (tk + 1 < NT);
        s16x8 bfr[4][2];
#pragma unroll
        for (int p = 0; p < 4; p++) {
            s16x8 af[2][2];
#pragma unroll
            for (int j = 0; j < 2; j++) {
                const char* rowp = (const char*)Al + (size_t)(wm * 128 + (2 * p + j) * 16 + lr) * 128;
#pragma unroll
                for (int kk = 0; kk < 2; kk++)
                    af[j][kk] = *(const s16x8*)(rowp + (((kk * 4 + g) ^ (lr & 7)) << 4));
            }
            if (p == 0) {
#pragma unroll
                for (int ni = 0; ni < 4; ni++) {
                    const char* rowp = (const char*)Bl + (size_t)(wn * 64 + ni * 16 + lr) * 128;
#pragma unroll
                    for (int kk = 0; kk < 2; kk++)
                        bfr[ni][kk] = *(const s16x8*)(rowp + (((kk * 4 + g) ^ (lr & 7)) << 4));
                }
            }
            if (pf) {
                gload16(Ag[p] + knext, &An[(w * 4 + p) * 512]);
                gload16(Bg[p] + knext, &Bn[(w * 4 + p) * 512]);
            }
            __builtin_amdgcn_s_barrier();
            __builtin_amdgcn_s_setprio(1);
#pragma unroll
            for (int j = 0; j < 2; j++)
#pragma unroll
                for (int ni = 0; ni < 4; ni++) {
                    acc[2 * p + j][ni] = __builtin_amdgcn_mfma_f32_16x16x32_bf16(af[j][0], bfr[ni][0], acc[2 * p + j][ni], 0, 0, 0);
                    acc[2 * p + j][ni] = __builtin_amdgcn_mfma_f32_16x16x32_bf16(af[j][1], bfr[ni][1], acc[2 * p + j][ni], 0, 0, 0);
                }
            __builtin_amdgcn_s_setprio(0);
            __builtin_amdgcn_s_barrier();
        }
        if (pf) asm volatile("s_waitcnt vmcnt(0)" ::: "memory");
        __builtin_amdgcn_s_barrier();
        asm volatile("" ::: "memory");
        cur ^= 1;
    }

    // ---- fused epilogue: bias + RMSNorm + RoPE, write Q/K/V final layouts ----
    const int head = (bcol >> 6) + wn;            // wave-uniform
    const float* bptr = (head < 32) ? (bq + head * 64)
                       : (head < 40) ? (bk + (head - 32) * 64)
                                     : (bv + (head - 40) * 64);
    const float bz0 = bptr[0 * 16 + lr], bz1 = bptr[1 * 16 + lr];
    const float bz2 = bptr[2 * 16 + lr], bz3 = bptr[3 * 16 + lr];
    const float nw0 = (head < 32) ? qn_w[0 * 16 + lr] : kn_w[0 * 16 + lr];
    const float nw1 = (head < 32) ? qn_w[1 * 16 + lr] : kn_w[1 * 16 + lr];
    const float nw2 = (head < 32) ? qn_w[2 * 16 + lr] : kn_w[2 * 16 + lr];
    const float nw3 = (head < 32) ? qn_w[3 * 16 + lr] : kn_w[3 * 16 + lr];
#pragma unroll
    for (int mi = 0; mi < 8; mi++) {
#pragma unroll
        for (int r = 0; r < 4; r++) {
            int row = brow + wm * 128 + mi * 16 + g * 4 + r;   // token
            int b = row >> 11, s = row & 2047;
            float v[4];
            v[0] = acc[mi][0][r] + bz0;
            v[1] = acc[mi][1][r] + bz1;
            v[2] = acc[mi][2][r] + bz2;
            v[3] = acc[mi][3][r] + bz3;
            if (head < 40) {
                float ss = v[0] * v[0] + v[1] * v[1] + v[2] * v[2] + v[3] * v[3];
                ss += __shfl_xor(ss, 1);
                ss += __shfl_xor(ss, 2);
                ss += __shfl_xor(ss, 4);
                ss += __shfl_xor(ss, 8);
                float rin = rsqrtf(ss * (1.0f / 64.0f) + 1e-6f);
                float xn[4];
                xn[0] = v[0] * rin * nw0;
                xn[1] = v[1] * rin * nw1;
                xn[2] = v[2] * rin * nw2;
                xn[3] = v[3] * rin * nw3;
                const float* cr = cosT + (size_t)s * HD;
                const float* sr = sinT + (size_t)s * HD;
                float o[4];
#pragma unroll
                for (int ni = 0; ni < 4; ni++) {
                    int d = ni * 16 + lr;
                    float part = xn[ni ^ 2];
                    float sign = (d < 32) ? -1.f : 1.f;
                    o[ni] = xn[ni] * cr[d] + sign * part * sr[d];
                }
                if (head < 32) {
                    u16* qrow = Qp + (((size_t)(b * NH + head) * SEQ + s) * HD);
#pragma unroll
                    for (int ni = 0; ni < 4; ni++) qrow[ni * 16 + lr] = f2bf(o[ni] * QSCALE);
                } else {
                    u16* krow = Kp + (((size_t)(b * NKV + head - 32) * SEQ + s) * HD);
#pragma unroll
                    for (int ni = 0; ni < 4; ni++) krow[ni * 16 + lr] = f2bf(o[ni]);
                }
            } else {
                u16* vrow = Vp + (((size_t)(b * NKV + head - 40) * SEQ + s) * HD);
#pragma unroll
                for (int ni = 0; ni < 4; ni++) vrow[ni * 16 + lr] = f2bf(v[ni]);
            }
        }
    }
}

// ---------------- GEMM: 128x256 8-wave pipelined (used for Wo, f32 out) ----------------
__global__ __launch_bounds__(512, 1) void k_gemm_wo(const u16* __restrict__ A, const u16* __restrict__ BT,
                                                    const float* __restrict__ bias, float* __restrict__ Cout,
                                                    int gxn, int K, int lda, int ldb, int N) {
    __shared__ u16 LA[2][128 * 64];
    __shared__ u16 LB[2][256 * 64];
    const int tid = threadIdx.x;
    const int w = tid >> 6, lane = tid & 63;
    const int wm = w >> 2, wn = w & 3;            // wave grid 2M x 4N
    const int lr = lane & 15, g = lane >> 4;
    const int nwg = gridDim.x;
    int bid = blockIdx.x;
    const int cpx = nwg >> 3;
    bid = (bid & 7) * cpx + (bid >> 3);           // XCD-bijective (nwg%8==0)
    const int brow = (bid / gxn) * 128, bcol = (bid % gxn) * 256;

    const int lrow8 = lane >> 3;
    const int gs = (lane & 7) ^ lrow8;
    const u16* Ag[2]; const u16* Bg[4];
#pragma unroll
    for (int p = 0; p < 2; p++) {
        int row = (w * 2 + p) * 8 + lrow8;
        Ag[p] = A + (size_t)(brow + row) * lda + gs * 8;
    }
#pragma unroll
    for (int p = 0; p < 4; p++) {
        int row = (w * 4 + p) * 8 + lrow8;
        Bg[p] = BT + (size_t)(bcol + row) * ldb + gs * 8;
    }

    f32x4 acc[4][4] = {};

#pragma unroll
    for (int p = 0; p < 2; p++) gload16(Ag[p], &LA[0][(w * 2 + p) * 512]);
#pragma unroll
    for (int p = 0; p < 4; p++) gload16(Bg[p], &LB[0][(w * 4 + p) * 512]);
    asm volatile("s_waitcnt vmcnt(0)" ::: "memory");
    __builtin_amdgcn_s_barrier();
    asm volatile("" ::: "memory");

    const int NT = K >> 6;
    int cur = 0;
    for (int tk = 0; tk < NT; tk++) {
        const u16* Al = &LA[cur][0];
        const u16* Bl = &LB[cur][0];
        u16* An = &LA[cur ^ 1][0];
        u16* Bn = &LB[cur ^ 1][0];
        const int knext = (tk + 1) << 6;
        const bool pf = (tk + 1 < NT);
        s16x8 bfr[4][2];
#pragma unroll
        for (int p = 0; p < 4; p++) {      // phase p computes mi = p
            s16x8 af[2];
            const char* rowpA = (const char*)Al + (size_t)(wm * 64 + p * 16 + lr) * 128;
#pragma unroll
            for (int kk = 0; kk < 2; kk++)
                af[kk] = *(const s16x8*)(rowpA + (((kk * 4 + g) ^ (lr & 7)) << 4));
            if (p == 0) {
#pragma unroll
                for (int ni = 0; ni < 4; ni++) {
                    const char* rowp = (const char*)Bl + (size_t)(wn * 64 + ni * 16 + lr) * 128;
#pragma unroll
                    for (int kk = 0; kk < 2; kk++)
                        bfr[ni][kk] = *(const s16x8*)(rowp + (((kk * 4 + g) ^ (lr & 7)) << 4));
                }
            }
            if (pf) {
                if (p == 0) {
                    gload16(Ag[0] + knext, &An[(w * 2 + 0) * 512]);
                    gload16(Ag[1] + knext, &An[(w * 2 + 1) * 512]);
                } else if (p == 1) {
                    gload16(Bg[0] + knext, &Bn[(w * 4 + 0) * 512]);
                    gload16(Bg[1] + knext, &Bn[(w * 4 + 1) * 512]);
                } else if (p == 2) {
                    gload16(Bg[2] + knext, &Bn[(w * 4 + 2) * 512]);
                    gload16(Bg[3] + knext, &Bn[(w * 4 + 3) * 512]);
                }
            }
            __builtin_amdgcn_s_barrier();
            __builtin_amdgcn_s_setprio(1);
#pragma unroll
            for (int ni = 0; ni < 4; ni++) {
                acc[p][ni] = __builtin_amdgcn_mfma_f32_16x16x32_bf16(af[0], bfr[ni][0], acc[p][ni], 0, 0, 0);
                acc[p][ni] = __builtin_amdgcn_mfma_f32_16x16x32_bf16(af[1], bfr[ni][1], acc[p][ni], 0, 0, 0);
            }
            __builtin_amdgcn_s_setprio(0);
            __builtin_amdgcn_s_barrier();
        }
        if (pf) asm volatile("s_waitcnt vmcnt(0)" ::: "memory");
        __builtin_amdgcn_s_barrier();
        asm volatile("" ::: "memory");
        cur ^= 1;
    }

#pragma unroll
    for (int mi = 0; mi < 4; mi++) {
#pragma unroll
        for (int ni = 0; ni < 4; ni++) {
#pragma unroll
            for (int r = 0; r < 4; r++) {
                int row = brow + wm * 64 + mi * 16 + g * 4 + r;
                int col = bcol + wn * 64 + ni * 16 + lr;
                Cout[(size_t)row * N + col] = acc[mi][ni][r] + bias[col];
            }
        }
    }
}

// ---------------- MFMA flash attention v4.1 (r17 verbatim, measured ~90us) ----------------
__global__ __launch_bounds__(256) void k_attn_mfma(const u16* __restrict__ Qp, const u16* __restrict__ Kp,
                                                   const u16* __restrict__ VpT, u16* __restrict__ AO) {
    __shared__ u16 K_lds[64 * 64];    // [key][d], 16B slots XOR'd by key&7
    __shared__ u16 VT_lds[64 * 64];   // [d][key], 16B slots XOR'd by d&7
    __shared__ u16 P_lds[4][32][76];  // per-wave, [q][key], pad 76
    const int bid = blockIdx.x;
    const int qt = 15 - (bid >> 6);   // heavy tiles first
    const int hh = bid & 63;
    const int b = hh >> 5, h = hh & 31, kvh = h >> 2;
    const int t = threadIdx.x, w = t >> 6, lane = t & 63;
    const int q5 = lane & 31, hi = lane >> 5;
    const int qwb = qt * 128 + w * 32;
    const int q_abs = qwb + q5;

    const u16* Qb = Qp + (size_t)(b * NH + h) * SEQ * HD;
    const u16* Kb = Kp + (size_t)(b * NKV + kvh) * SEQ * HD;
    const u16* Vb = VpT + (size_t)(b * NKV + kvh) * HD * SEQ;

    s16x8 qf0 = *(const s16x8*)(Qb + (size_t)q_abs * HD + 0 * 16 + hi * 8);
    s16x8 qf1 = *(const s16x8*)(Qb + (size_t)q_abs * HD + 1 * 16 + hi * 8);
    s16x8 qf2 = *(const s16x8*)(Qb + (size_t)q_abs * HD + 2 * 16 + hi * 8);
    s16x8 qf3 = *(const s16x8*)(Qb + (size_t)q_abs * HD + 3 * 16 + hi * 8);

    f32x16 O0, O1;
#pragma unroll
    for (int r = 0; r < 16; r++) { O0[r] = 0.f; O1[r] = 0.f; }
    float m = -1e30f, l = 0.f;

    const int swz = (q5 & 7) << 4;
    const int nkt = 2 * (qt + 1);
    for (int kt = 0; kt < nkt; kt++) {
        const int k0 = kt * 64;
        __syncthreads();
#pragma unroll
        for (int i = 0; i < 2; i++) {
            int c = (w * 2 + i) * 64 + lane;
            int row = c >> 3, gslot = (c & 7) ^ (row & 7);
            gload16(Kb + (size_t)(k0 + row) * HD + gslot * 8, (char*)K_lds + (size_t)(w * 2 + i) * 1024);
            gload16(Vb + (size_t)row * SEQ + k0 + gslot * 8, (char*)VT_lds + (size_t)(w * 2 + i) * 1024);
        }
        __syncthreads();
        if (k0 > qwb + 31) continue;

        f32x16 s0, s1;
#pragma unroll
        for (int r = 0; r < 16; r++) { s0[r] = 0.f; s1[r] = 0.f; }
        __builtin_amdgcn_s_setprio(1);
#pragma unroll
        for (int dblk = 0; dblk < 4; dblk++) {
            s16x8 kf0 = *(const s16x8*)((const char*)K_lds + q5 * 128 + ((dblk * 32 + hi * 16) ^ swz));
            s16x8 kf1 = *(const s16x8*)((const char*)K_lds + (32 + q5) * 128 + ((dblk * 32 + hi * 16) ^ swz));
            s16x8 qq = (dblk == 0) ? qf0 : (dblk == 1) ? qf1 : (dblk == 2) ? qf2 : qf3;
            s0 = __builtin_amdgcn_mfma_f32_32x32x16_bf16(kf0, qq, s0, 0, 0, 0);
            s1 = __builtin_amdgcn_mfma_f32_32x32x16_bf16(kf1, qq, s1, 0, 0, 0);
        }
        __builtin_amdgcn_s_setprio(0);

        if (k0 + 63 > qwb) {
            const int qrel = q_abs - k0;
#pragma unroll
            for (int r = 0; r < 16; r++) {
                int kr = (r & 3) + 8 * (r >> 2) + 4 * hi;
                if (kr > qrel) s0[r] = -1e30f;
                if (kr + 32 > qrel) s1[r] = -1e30f;
            }
        }

        float mt = -1e30f;
#pragma unroll
        for (int r = 0; r < 16; r++) { mt = fmaxf(mt, s0[r]); mt = fmaxf(mt, s1[r]); }
        mt = fmaxf(mt, __shfl_xor(mt, 32));
        if (!__all(mt <= m + 8.0f)) {
            float mn = fmaxf(m, mt);
            float f = exp2f(m - mn);
            l *= f;
#pragma unroll
            for (int r = 0; r < 16; r++) { O0[r] *= f; O1[r] *= f; }
            m = mn;
        }
        float ps = 0.f;
#pragma unroll
        for (int r = 0; r < 16; r++) {
            float p0 = exp2f(s0[r] - m);
            float p1 = exp2f(s1[r] - m);
            s0[r] = p0; s1[r] = p1;
            ps += p0 + p1;
        }
        ps += __shfl_xor(ps, 32);
        l += ps;

#pragma unroll
        for (int i = 0; i < 8; i++) {
            int key = 2 * (i & 1) + 8 * (i >> 1) + 4 * hi;
            *(unsigned*)&P_lds[w][q5][key]      = cvtpk(s0[2 * i], s0[2 * i + 1]);
            *(unsigned*)&P_lds[w][q5][key + 32] = cvtpk(s1[2 * i], s1[2 * i + 1]);
        }

        __builtin_amdgcn_s_setprio(1);
#pragma unroll
        for (int ks = 0; ks < 4; ks++) {
            s16x8 pb  = *(const s16x8*)&P_lds[w][q5][ks * 16 + hi * 8];
            s16x8 vf0 = *(const s16x8*)((const char*)VT_lds + q5 * 128 + ((ks * 32 + hi * 16) ^ swz));
            s16x8 vf1 = *(const s16x8*)((const char*)VT_lds + (32 + q5) * 128 + ((ks * 32 + hi * 16) ^ swz));
            O0 = __builtin_amdgcn_mfma_f32_32x32x16_bf16(vf0, pb, O0, 0, 0, 0);
            O1 = __builtin_amdgcn_mfma_f32_32x32x16_bf16(vf1, pb, O1, 0, 0, 0);
        }
        __builtin_amdgcn_s_setprio(0);
    }

    float inv = 1.0f / l;
    u16* orow = AO + (size_t)(b * SEQ + q_abs) * (NH * HD) + h * HD;
#pragma unroll
    for (int db = 0; db < 2; db++) {
#pragma unroll
        for (int g2 = 0; g2 < 4; g2++) {
            u16x4 wv;
#pragma unroll
            for (int i2 = 0; i2 < 4; i2++) {
                float v = (db == 0 ? O0[g2 * 4 + i2] : O1[g2 * 4 + i2]) * inv;
                wv[i2] = f2bf(v);
            }
            *(u16x4*)(orow + db * 32 + g2 * 8 + hi * 4) = wv;
        }
    }
}

// ---------------- launch ----------------
extern "C" void kernel_launch(void* const* d_in, const int* in_sizes, int n_in,
                              void* d_out, int out_size, void* d_ws, size_t ws_size,
                              hipStream_t stream) {
    const float* hs   = (const float*)d_in[0];
    const float* Wq   = (const float*)d_in[1];
    const float* bq   = (const float*)d_in[2];
    const float* Wk   = (const float*)d_in[3];
    const float* bk   = (const float*)d_in[4];
    const float* Wv   = (const float*)d_in[5];
    const float* bv   = (const float*)d_in[6];
    const float* Wo   = (const float*)d_in[7];
    const float* bo   = (const float*)d_in[8];
    const float* qn_w = (const float*)d_in[9];
    const float* kn_w = (const float*)d_in[10];
    const float* cosT = (const float*)d_in[11];
    const float* sinT = (const float*)d_in[12];

    char* ws = (char*)d_ws;
    size_t off = 0;
    auto alloc = [&](size_t bytes) { char* p = ws + off; off = (off + bytes + 255) & ~(size_t)255; return p; };
    u16*   Xb    = (u16*)  alloc((size_t)TOK * HID * 2);
    u16*   WTqkv = (u16*)  alloc((size_t)NQKV * HID * 2);
    u16*   WoT   = (u16*)  alloc((size_t)HID * HID * 2);
    u16*   Qp    = (u16*)  alloc((size_t)BATCH * NH * SEQ * HD * 2);
    u16*   Kp    = (u16*)  alloc((size_t)BATCH * NKV * SEQ * HD * 2);
    u16*   Vp    = (u16*)  alloc((size_t)BATCH * NKV * SEQ * HD * 2);
    u16*   VpT   = (u16*)  alloc((size_t)BATCH * NKV * SEQ * HD * 2);
    u16*   AO    = (u16*)  alloc((size_t)TOK * HID * 2);
    (void)ws_size;

    dim3 tb(32, 8);
    // weight transposes + X conversion in one dispatch
    k_prep<<<dim3(64, 64, 5), tb, 0, stream>>>(Wq, Wk, Wv, Wo, hs, WTqkv, WoT, Xb);
    // QKV GEMM (256^2 pipelined) + fused bias/RMSNorm/RoPE: grid 192 (%8==0)
    k_gemm256_qkv<<<dim3((TOK / 256) * (NQKV / 256)), 512, 0, stream>>>(
        Xb, WTqkv, bq, bk, bv, qn_w, kn_w, cosT, sinT, Qp, Kp, Vp, NQKV / 256, HID, HID, HID);
    // V transpose per head
    k_transpose_v<<<dim3(HD / 32, SEQ / 32, BATCH * NKV), tb, 0, stream>>>(Vp, VpT);
    // MFMA flash attention (r17 verbatim)
    k_attn_mfma<<<BATCH * NH * (SEQ / 128), 256, 0, stream>>>(Qp, Kp, VpT, AO);
    // output projection (128x256 pipelined) -> f32 d_out: grid 32*8 = 256 blocks (%8==0)
    k_gemm_wo<<<dim3((TOK / 128) * (HID / 256)), 512, 0, stream>>>(AO, WoT, bo, (float*)d_out,
                                                                    HID / 256, HID, HID, HID, HID);
}